// Round 6
// baseline (289.562 us; speedup 1.0000x reference)
//
#include <hip/hip_runtime.h>
#include <hip/hip_bf16.h>
#include <stdint.h>

#define Bb 8
#define Nn 16384
#define Cc 40
#define Ee 512
#define Dd 256

typedef __attribute__((ext_vector_type(4))) float f32x4;
typedef __attribute__((ext_vector_type(8))) short bf16x8;

__device__ __forceinline__ unsigned short f2bf(float f) {
  union { float f; uint32_t u; } x; x.f = f;
  uint32_t r = x.u + 0x7FFFu + ((x.u >> 16) & 1u);   // round-to-nearest-even
  return (unsigned short)(r >> 16);
}
__device__ __forceinline__ unsigned int pack2(float a, float b) {
  return (unsigned int)f2bf(a) | ((unsigned int)f2bf(b) << 16);
}
__device__ __forceinline__ bf16x8 q2bf(float4 a, float4 c) {
  union { __hip_bfloat162 h2[4]; bf16x8 v; } u;
  u.h2[0] = __float22bfloat162_rn(float2{a.x, a.y});
  u.h2[1] = __float22bfloat162_rn(float2{a.z, a.w});
  u.h2[2] = __float22bfloat162_rn(float2{c.x, c.y});
  u.h2[3] = __float22bfloat162_rn(float2{c.z, c.w});
  return u.v;
}

// ---------------- prepA: Mt[z][d][e] = sum_{f half z} Wq[f][e]*Wk[f][d];
//                  plus (bx==8,bz==0): tvec/uvec/bqbk bias vectors ----------------
// grid (9,4,2), 256 thr.
__global__ __launch_bounds__(256) void prepA_kernel(
    const float* __restrict__ Wq, const float* __restrict__ Wk,
    const float* __restrict__ bq, const float* __restrict__ bk,
    float* __restrict__ Mt, float* __restrict__ tvec,
    float* __restrict__ uvec, float* __restrict__ bqbk) {
  const int t = threadIdx.x;
  if (blockIdx.x == 8) {
    if (blockIdx.z != 0) return;
    const int by = blockIdx.y;
    if (by < 2) {
      const int e = by * 256 + t;
      float s = 0.f;
      #pragma unroll 8
      for (int f = 0; f < Ee; f++) s += Wq[(size_t)f * Ee + e] * bk[f];
      tvec[e] = s;
    } else if (by == 2) {
      const int d = t;
      float s = 0.f;
      #pragma unroll 8
      for (int f = 0; f < Ee; f++) s += Wk[(size_t)f * Dd + d] * bq[f];
      uvec[d] = s;
    } else {
      __shared__ float red[256];
      float p = 0.f;
      for (int f = t; f < Ee; f += 256) p += bq[f] * bk[f];
      red[t] = p; __syncthreads();
      #pragma unroll
      for (int off = 128; off > 0; off >>= 1) {
        if (t < off) red[t] += red[t + off];
        __syncthreads();
      }
      if (t == 0) bqbk[0] = red[0];
    }
    return;
  }
  __shared__ float WqL[64][68];
  __shared__ float WkL[64][68];
  const int te = (t & 15) * 4;
  const int td = (t >> 4) * 4;
  const int ebase = blockIdx.x * 64, dbase = blockIdx.y * 64;
  const int fbase = blockIdx.z * 256;
  f32x4 acc0 = {0,0,0,0}, acc1 = {0,0,0,0}, acc2 = {0,0,0,0}, acc3 = {0,0,0,0};
  for (int f0 = 0; f0 < 256; f0 += 64) {
    __syncthreads();
    #pragma unroll
    for (int i = 0; i < 4; i++) {
      int idx = t + i * 256;
      int row = idx >> 4, c4 = (idx & 15) * 4;
      *(float4*)&WqL[row][c4] = *(const float4*)(Wq + (size_t)(fbase + f0 + row) * Ee + ebase + c4);
      *(float4*)&WkL[row][c4] = *(const float4*)(Wk + (size_t)(fbase + f0 + row) * Dd + dbase + c4);
    }
    __syncthreads();
    #pragma unroll 8
    for (int ff = 0; ff < 64; ff++) {
      float4 a = *(const float4*)&WkL[ff][td];
      float4 b = *(const float4*)&WqL[ff][te];
      acc0[0] += a.x*b.x; acc0[1] += a.x*b.y; acc0[2] += a.x*b.z; acc0[3] += a.x*b.w;
      acc1[0] += a.y*b.x; acc1[1] += a.y*b.y; acc1[2] += a.y*b.z; acc1[3] += a.y*b.w;
      acc2[0] += a.z*b.x; acc2[1] += a.z*b.y; acc2[2] += a.z*b.z; acc2[3] += a.z*b.w;
      acc3[0] += a.w*b.x; acc3[1] += a.w*b.y; acc3[2] += a.w*b.z; acc3[3] += a.w*b.w;
    }
  }
  float* mt = Mt + (size_t)blockIdx.z * 131072;
  *(f32x4*)&mt[(size_t)(dbase + td + 0) * Ee + ebase + te] = acc0;
  *(f32x4*)&mt[(size_t)(dbase + td + 1) * Ee + ebase + te] = acc1;
  *(f32x4*)&mt[(size_t)(dbase + td + 2) * Ee + ebase + te] = acc2;
  *(f32x4*)&mt[(size_t)(dbase + td + 3) * Ee + ebase + te] = acc3;
}

// ---------------- prepB: bx<48 -> A-frags(G)+dbias; bx>=48 -> B-frags(vp) --------
// grid (112,4), 256 thr.
__global__ __launch_bounds__(256) void prepB_kernel(
    const float* __restrict__ k, const float* __restrict__ v,
    const float* __restrict__ Wv, const float* __restrict__ bv,
    const float* __restrict__ Mt, const float* __restrict__ tvec,
    const float* __restrict__ uvec, const float* __restrict__ bqbk,
    unsigned short* __restrict__ abf, unsigned short* __restrict__ vpf,
    float* __restrict__ dbias) {
  __shared__ float xL[8][Dd];
  const int t = threadIdx.x;
  const int el = t & 127, half = t >> 7;
  const int e = blockIdx.y * 128 + el;

  if (blockIdx.x < 48) {
    const int sbase = blockIdx.x * 8;
    for (int i = t; i < 8 * Dd; i += 256) {
      int row = i >> 8, dd = i & (Dd - 1);
      int sg = sbase + row, bb_ = sg / 48, cc = sg % 48;
      xL[row][dd] = (cc < 40) ? k[((size_t)bb_ * Cc + cc) * Dd + dd] : 0.f;
    }
    __syncthreads();
    float acc[4] = {0,0,0,0};
    float db[4]  = {0,0,0,0};
    #pragma unroll 8
    for (int d = 0; d < Dd; d++) {
      float mt = Mt[(size_t)d * Ee + e] + Mt[131072 + (size_t)d * Ee + e];
      float ud = uvec[d];
      #pragma unroll
      for (int si = 0; si < 4; si++) {
        float kv = xL[half*4 + si][d];
        acc[si] += mt * kv;
        db[si]  += ud * kv;
      }
    }
    const float scale = 0.044194173824159216f;  // 1/sqrt(512)
    const float te = tvec[e];
    const float bqbkv = bqbk[0];
    const int ks = e >> 5, gg = (e >> 3) & 3, j = e & 7;
    #pragma unroll
    for (int si = 0; si < 4; si++) {
      int sg = sbase + half*4 + si, bb_ = sg / 48, cc = sg % 48;
      int ct = cc >> 4, lane16 = (cc & 15) + 16*gg;
      unsigned short val = (cc < 40) ? f2bf(scale * (acc[si] + te)) : (unsigned short)0;
      abf[((((size_t)bb_*3 + ct)*16 + ks)*64 + lane16)*8 + j] = val;
      if (el == 0) dbias[bb_*64 + cc] = (cc < 40) ? scale * (db[si] + bqbkv) : 0.f;
    }
  } else {
    const int sbase = (blockIdx.x - 48) * 8;
    for (int i = t; i < 8 * Dd; i += 256) {
      int row = i >> 8, dd = i & (Dd - 1);
      int sg = sbase + row, bb_ = sg >> 6, cc = sg & 63;
      xL[row][dd] = (cc < 40) ? v[((size_t)bb_ * Cc + cc) * Dd + dd] : 0.f;
    }
    __syncthreads();
    const float* wrow = Wv + (size_t)e * Dd;
    float acc[4] = {0,0,0,0};
    #pragma unroll 2
    for (int dd = 0; dd < Dd; dd += 4) {
      float4 w = *(const float4*)(wrow + dd);
      #pragma unroll
      for (int si = 0; si < 4; si++) {
        float4 vv = *(const float4*)&xL[half*4 + si][dd];
        acc[si] += w.x*vv.x + w.y*vv.y + w.z*vv.z + w.w*vv.w;
      }
    }
    const float bve = bv[e];
    const int nt = e >> 4, elan = e & 15;
    #pragma unroll
    for (int si = 0; si < 4; si++) {
      int sg = sbase + half*4 + si, bb_ = sg >> 6, cc = sg & 63;
      int s = cc >> 5, gg = (cc >> 3) & 3, j = cc & 7;
      unsigned short val = (cc < 40) ? f2bf(acc[si] + bve) : (unsigned short)0;
      vpf[((((size_t)bb_*32 + nt)*2 + s)*64 + (elan + 16*gg))*8 + j] = val;
    }
  }
}

// ---------------- main: abf in LDS; vpf from L2; 8 waves/block; 2 blocks/CU ------
// grid 512: block = (b = bx>>6, seg = bx&63); block does 256 rows = 8w x 2it x 16.
__global__ __launch_bounds__(512, 4) void main_kernel(
    const float* __restrict__ q, const float* __restrict__ coarse,
    const unsigned short* __restrict__ abfrag,
    const unsigned short* __restrict__ vpfrag,
    const float* __restrict__ dbias, float* __restrict__ out) {
  __shared__ uint4 abL[3072];                   // 48 KB A-fragments (G)
  __shared__ unsigned short s_att[8][16][72];   // 18 KB per-wave attn re-fragment
  const int t = threadIdx.x;
  const int wave = t >> 6, lane = t & 63;
  const int r = lane & 15, g = lane >> 4;
  const int b = blockIdx.x >> 6;
  const int seg = blockIdx.x & 63;
  const bool v2 = (g < 2);

  // dbias (per batch, hoisted; latency hides under staging)
  const float4 db0 = *(const float4*)(dbias + b*64 +  0 + 4*g);
  const float4 db1 = *(const float4*)(dbias + b*64 + 16 + 4*g);
  const float4 db2 = *(const float4*)(dbias + b*64 + 32 + 4*g);

  // ---- stage A-fragments to LDS (once per block) ----
  {
    const uint4* srcA = (const uint4*)abfrag + (size_t)b * 3072;
    #pragma unroll
    for (int i = 0; i < 6; i++) abL[t + i*512] = srcA[t + i*512];
  }
  __syncthreads();

  const int row0 = seg * 256 + wave * 16;
  const float* qrow0 = q + ((size_t)b * Nn + row0 + r) * Ee + 8 * g;
  const float* cbase0 = coarse + (size_t)b * Cc * Nn + row0 + r;
  float* outb0 = out + ((size_t)b * Nn + row0 + r) * Ee + 4 * g;
  const bf16x8* vpb = (const bf16x8*)vpfrag + (size_t)b * 4096 + lane;

  f32x4 acc0, acc1, acc2;
  float4 QA[8], QB[8];

  auto LOADQ = [&](const float* qr, int qi, float4* Q) {
    #pragma unroll
    for (int j = 0; j < 4; j++) {
      Q[2*j]   = *(const float4*)(qr + 128*qi + 32*j);
      Q[2*j+1] = *(const float4*)(qr + 128*qi + 32*j + 4);
    }
  };
  auto COMPQ = [&](const float4* Q, int qi) {
    #pragma unroll
    for (int j = 0; j < 4; j++) {
      bf16x8 qf = q2bf(Q[2*j], Q[2*j+1]);
      const int ks = 4*qi + j;
      acc0 = __builtin_amdgcn_mfma_f32_16x16x32_bf16(*(const bf16x8*)&abL[(0*16+ks)*64 + lane], qf, acc0, 0,0,0);
      acc1 = __builtin_amdgcn_mfma_f32_16x16x32_bf16(*(const bf16x8*)&abL[(1*16+ks)*64 + lane], qf, acc1, 0,0,0);
      acc2 = __builtin_amdgcn_mfma_f32_16x16x32_bf16(*(const bf16x8*)&abL[(2*16+ks)*64 + lane], qf, acc2, 0,0,0);
    }
  };

  LOADQ(qrow0, 0, QA);   // prologue

  for (int it = 0; it < 2; it++) {
    const float* qr = qrow0 + (size_t)(it*128) * Ee;
    LOADQ(qr, 1, QB);

    // coarse_pred loads (independent; latency hides under COMP)
    const float* cb = cbase0 + it*128;
    float cr[3][4];
    #pragma unroll
    for (int rg = 0; rg < 4; rg++) {
      cr[0][rg] = cb[(size_t)( 0 + 4*g + rg) * Nn];
      cr[1][rg] = cb[(size_t)(16 + 4*g + rg) * Nn];
      cr[2][rg] = v2 ? cb[(size_t)(32 + 4*g + rg) * Nn] : -3e38f;
    }

    acc0 = f32x4{0,0,0,0}; acc1 = f32x4{0,0,0,0}; acc2 = f32x4{0,0,0,0};
    COMPQ(QA, 0); LOADQ(qr, 2, QA);
    COMPQ(QB, 1); LOADQ(qr, 3, QB);
    COMPQ(QA, 2);
    COMPQ(QB, 3);

    float L[3][4];
    #pragma unroll
    for (int rg = 0; rg < 4; rg++) {
      L[0][rg] = acc0[rg] + ((const float*)&db0)[rg];
      L[1][rg] = acc1[rg] + ((const float*)&db1)[rg];
      L[2][rg] = acc2[rg] + ((const float*)&db2)[rg];
    }

    // ---- softmax #1 over c ----
    float m1 = -3e38f;
    #pragma unroll
    for (int rg = 0; rg < 4; rg++) {
      m1 = fmaxf(m1, L[0][rg]); m1 = fmaxf(m1, L[1][rg]);
      if (v2) m1 = fmaxf(m1, L[2][rg]);
    }
    m1 = fmaxf(m1, __shfl_xor(m1, 16));
    m1 = fmaxf(m1, __shfl_xor(m1, 32));
    float p[3][4]; float s1 = 0.f;
    #pragma unroll
    for (int rg = 0; rg < 4; rg++) {
      p[0][rg] = __expf(L[0][rg] - m1); s1 += p[0][rg];
      p[1][rg] = __expf(L[1][rg] - m1); s1 += p[1][rg];
      p[2][rg] = v2 ? __expf(L[2][rg] - m1) : 0.f; s1 += p[2][rg];
    }
    s1 += __shfl_xor(s1, 16); s1 += __shfl_xor(s1, 32);
    const float inv1 = 1.0f / s1;

    // ---- cp = softmax_c(coarse_pred) ----
    float m2 = -3e38f;
    #pragma unroll
    for (int rg = 0; rg < 4; rg++) {
      m2 = fmaxf(m2, cr[0][rg]); m2 = fmaxf(m2, cr[1][rg]);
      if (v2) m2 = fmaxf(m2, cr[2][rg]);
    }
    m2 = fmaxf(m2, __shfl_xor(m2, 16));
    m2 = fmaxf(m2, __shfl_xor(m2, 32));
    float cpv[3][4]; float s2 = 0.f;
    #pragma unroll
    for (int rg = 0; rg < 4; rg++) {
      cpv[0][rg] = __expf(cr[0][rg] - m2); s2 += cpv[0][rg];
      cpv[1][rg] = __expf(cr[1][rg] - m2); s2 += cpv[1][rg];
      cpv[2][rg] = v2 ? __expf(cr[2][rg] - m2) : 0.f; s2 += cpv[2][rg];
    }
    s2 += __shfl_xor(s2, 16); s2 += __shfl_xor(s2, 32);
    const float inv2 = 1.0f / s2;

    // ---- softmax #2 over c of (attn1 * cp) ----
    const float sc12 = inv1 * inv2;
    float w[3][4];
    float m3 = -3e38f;
    #pragma unroll
    for (int rg = 0; rg < 4; rg++) {
      w[0][rg] = p[0][rg] * cpv[0][rg] * sc12;
      w[1][rg] = p[1][rg] * cpv[1][rg] * sc12;
      w[2][rg] = v2 ? (p[2][rg] * cpv[2][rg] * sc12) : 0.f;
      m3 = fmaxf(m3, w[0][rg]); m3 = fmaxf(m3, w[1][rg]);
      if (v2) m3 = fmaxf(m3, w[2][rg]);
    }
    m3 = fmaxf(m3, __shfl_xor(m3, 16));
    m3 = fmaxf(m3, __shfl_xor(m3, 32));
    float p3[3][4]; float s3 = 0.f;
    #pragma unroll
    for (int rg = 0; rg < 4; rg++) {
      p3[0][rg] = __expf(w[0][rg] - m3); s3 += p3[0][rg];
      p3[1][rg] = __expf(w[1][rg] - m3); s3 += p3[1][rg];
      p3[2][rg] = v2 ? __expf(w[2][rg] - m3) : 0.f; s3 += p3[2][rg];
    }
    s3 += __shfl_xor(s3, 16); s3 += __shfl_xor(s3, 32);
    const float inv3 = 1.0f / s3;

    // ---- prefetch next tile's first q-quarter before the PV phase ----
    if (it < 1) LOADQ(qrow0 + (size_t)((it+1)*128) * Ee, 0, QA);

    // ---- re-fragment attn2 via per-wave LDS round-trip ----
    unsigned int* srow = (unsigned int*)&s_att[wave][r][0];
    #pragma unroll
    for (int ct = 0; ct < 3; ct++) {
      srow[8*ct + 2*g + 0] = pack2(p3[ct][0]*inv3, p3[ct][1]*inv3);
      srow[8*ct + 2*g + 1] = pack2(p3[ct][2]*inv3, p3[ct][3]*inv3);
    }
    srow[24 + 2*g + 0] = 0u;   // c = 48..63 zero pad
    srow[24 + 2*g + 1] = 0u;
    asm volatile("s_waitcnt lgkmcnt(0)" ::: "memory");
    const bf16x8 pa0 = *(const bf16x8*)&s_att[wave][r][ 0 + 8*g];
    const bf16x8 pa1 = *(const bf16x8*)&s_att[wave][r][32 + 8*g];

    // ---- PV transposed, vpf from L2, depth-2 register pipeline ----
    float* outp = outb0 + (size_t)(it*128) * Ee;
    bf16x8 va0 = vpb[0], va1 = vpb[64];
    #pragma unroll
    for (int nt = 0; nt < 32; nt++) {
      bf16x8 vb0, vb1;
      if (nt < 31) { vb0 = vpb[(nt+1)*128]; vb1 = vpb[(nt+1)*128 + 64]; }
      f32x4 o = {0,0,0,0};
      o = __builtin_amdgcn_mfma_f32_16x16x32_bf16(va0, pa0, o, 0,0,0);
      o = __builtin_amdgcn_mfma_f32_16x16x32_bf16(va1, pa1, o, 0,0,0);
      *(f32x4*)(outp + nt*16) = o;   // out[row r][nt*16 + 4g .. +3]
      va0 = vb0; va1 = vb1;
    }
  }
}

extern "C" void kernel_launch(void* const* d_in, const int* in_sizes, int n_in,
                              void* d_out, int out_size, void* d_ws, size_t ws_size,
                              hipStream_t stream) {
  const float* q   = (const float*)d_in[0];
  const float* k   = (const float*)d_in[1];
  const float* v   = (const float*)d_in[2];
  const float* cps = (const float*)d_in[3];
  const float* Wq  = (const float*)d_in[4];
  const float* bq  = (const float*)d_in[5];
  const float* Wk  = (const float*)d_in[6];
  const float* bk  = (const float*)d_in[7];
  const float* Wv  = (const float*)d_in[8];
  const float* bv  = (const float*)d_in[9];
  float* out = (float*)d_out;
  char* ws = (char*)d_ws;

  // ws layout (~1.97 MB total)
  float*          Mt    = (float*)(ws);                        // 2*256*512*4 = 1048576
  float*          tvec  = (float*)(ws + 1048576);              // 512*4  = 2048
  float*          uvec  = (float*)(ws + 1050624);              // 256*4  = 1024
  float*          bqbkp = (float*)(ws + 1051648);              // 4 (pad to 1024)
  unsigned short* abf   = (unsigned short*)(ws + 1052672);     // 393216
  unsigned short* vpf   = (unsigned short*)(ws + 1052672 + 393216);          // 524288
  float*          dbias = (float*)(ws + 1052672 + 393216 + 524288);          // 2048

  prepA_kernel<<<dim3(9, 4, 2), 256, 0, stream>>>(Wq, Wk, bq, bk, Mt, tvec, uvec, bqbkp);
  prepB_kernel<<<dim3(112, 4),  256, 0, stream>>>(k, v, Wv, bv, Mt, tvec, uvec, bqbkp,
                                                  abf, vpf, dbias);
  main_kernel <<<dim3(512),     512, 0, stream>>>(q, cps, abf, vpf, dbias, out);
}

// Round 7
// 213.125 us; speedup vs baseline: 1.3586x; 1.3586x over previous
//
#include <hip/hip_runtime.h>
#include <hip/hip_bf16.h>
#include <stdint.h>

#define Bb 8
#define Nn 16384
#define Cc 40
#define Ee 512
#define Dd 256

typedef __attribute__((ext_vector_type(4))) float f32x4;
typedef __attribute__((ext_vector_type(8))) short bf16x8;

__device__ __forceinline__ unsigned short f2bf(float f) {
  union { float f; uint32_t u; } x; x.f = f;
  uint32_t r = x.u + 0x7FFFu + ((x.u >> 16) & 1u);   // round-to-nearest-even
  return (unsigned short)(r >> 16);
}
__device__ __forceinline__ unsigned int pack2(float a, float b) {
  return (unsigned int)f2bf(a) | ((unsigned int)f2bf(b) << 16);
}
__device__ __forceinline__ bf16x8 q2bf(float4 a, float4 c) {
  union { __hip_bfloat162 h2[4]; bf16x8 v; } u;
  u.h2[0] = __float22bfloat162_rn(float2{a.x, a.y});
  u.h2[1] = __float22bfloat162_rn(float2{a.z, a.w});
  u.h2[2] = __float22bfloat162_rn(float2{c.x, c.y});
  u.h2[3] = __float22bfloat162_rn(float2{c.z, c.w});
  return u.v;
}

// ---------------- prepA: Mt[z][d][e] = sum_{f half z} Wq[f][e]*Wk[f][d];
//                  plus (bx==8,bz==0): tvec/uvec/bqbk bias vectors ----------------
// grid (9,4,2), 256 thr.
__global__ __launch_bounds__(256) void prepA_kernel(
    const float* __restrict__ Wq, const float* __restrict__ Wk,
    const float* __restrict__ bq, const float* __restrict__ bk,
    float* __restrict__ Mt, float* __restrict__ tvec,
    float* __restrict__ uvec, float* __restrict__ bqbk) {
  const int t = threadIdx.x;
  if (blockIdx.x == 8) {
    if (blockIdx.z != 0) return;
    const int by = blockIdx.y;
    if (by < 2) {
      const int e = by * 256 + t;
      float s = 0.f;
      #pragma unroll 8
      for (int f = 0; f < Ee; f++) s += Wq[(size_t)f * Ee + e] * bk[f];
      tvec[e] = s;
    } else if (by == 2) {
      const int d = t;
      float s = 0.f;
      #pragma unroll 8
      for (int f = 0; f < Ee; f++) s += Wk[(size_t)f * Dd + d] * bq[f];
      uvec[d] = s;
    } else {
      __shared__ float red[256];
      float p = 0.f;
      for (int f = t; f < Ee; f += 256) p += bq[f] * bk[f];
      red[t] = p; __syncthreads();
      #pragma unroll
      for (int off = 128; off > 0; off >>= 1) {
        if (t < off) red[t] += red[t + off];
        __syncthreads();
      }
      if (t == 0) bqbk[0] = red[0];
    }
    return;
  }
  __shared__ float WqL[64][68];
  __shared__ float WkL[64][68];
  const int te = (t & 15) * 4;
  const int td = (t >> 4) * 4;
  const int ebase = blockIdx.x * 64, dbase = blockIdx.y * 64;
  const int fbase = blockIdx.z * 256;
  f32x4 acc0 = {0,0,0,0}, acc1 = {0,0,0,0}, acc2 = {0,0,0,0}, acc3 = {0,0,0,0};
  for (int f0 = 0; f0 < 256; f0 += 64) {
    __syncthreads();
    #pragma unroll
    for (int i = 0; i < 4; i++) {
      int idx = t + i * 256;
      int row = idx >> 4, c4 = (idx & 15) * 4;
      *(float4*)&WqL[row][c4] = *(const float4*)(Wq + (size_t)(fbase + f0 + row) * Ee + ebase + c4);
      *(float4*)&WkL[row][c4] = *(const float4*)(Wk + (size_t)(fbase + f0 + row) * Dd + dbase + c4);
    }
    __syncthreads();
    #pragma unroll 8
    for (int ff = 0; ff < 64; ff++) {
      float4 a = *(const float4*)&WkL[ff][td];
      float4 b = *(const float4*)&WqL[ff][te];
      acc0[0] += a.x*b.x; acc0[1] += a.x*b.y; acc0[2] += a.x*b.z; acc0[3] += a.x*b.w;
      acc1[0] += a.y*b.x; acc1[1] += a.y*b.y; acc1[2] += a.y*b.z; acc1[3] += a.y*b.w;
      acc2[0] += a.z*b.x; acc2[1] += a.z*b.y; acc2[2] += a.z*b.z; acc2[3] += a.z*b.w;
      acc3[0] += a.w*b.x; acc3[1] += a.w*b.y; acc3[2] += a.w*b.z; acc3[3] += a.w*b.w;
    }
  }
  float* mt = Mt + (size_t)blockIdx.z * 131072;
  *(f32x4*)&mt[(size_t)(dbase + td + 0) * Ee + ebase + te] = acc0;
  *(f32x4*)&mt[(size_t)(dbase + td + 1) * Ee + ebase + te] = acc1;
  *(f32x4*)&mt[(size_t)(dbase + td + 2) * Ee + ebase + te] = acc2;
  *(f32x4*)&mt[(size_t)(dbase + td + 3) * Ee + ebase + te] = acc3;
}

// ---------------- prepB: bx<48 -> A-frags(G)+dbias; bx>=48 -> B-frags(vp) --------
// grid (112,4), 256 thr.
__global__ __launch_bounds__(256) void prepB_kernel(
    const float* __restrict__ k, const float* __restrict__ v,
    const float* __restrict__ Wv, const float* __restrict__ bv,
    const float* __restrict__ Mt, const float* __restrict__ tvec,
    const float* __restrict__ uvec, const float* __restrict__ bqbk,
    unsigned short* __restrict__ abf, unsigned short* __restrict__ vpf,
    float* __restrict__ dbias) {
  __shared__ float xL[8][Dd];
  const int t = threadIdx.x;
  const int el = t & 127, half = t >> 7;
  const int e = blockIdx.y * 128 + el;

  if (blockIdx.x < 48) {
    const int sbase = blockIdx.x * 8;
    for (int i = t; i < 8 * Dd; i += 256) {
      int row = i >> 8, dd = i & (Dd - 1);
      int sg = sbase + row, bb_ = sg / 48, cc = sg % 48;
      xL[row][dd] = (cc < 40) ? k[((size_t)bb_ * Cc + cc) * Dd + dd] : 0.f;
    }
    __syncthreads();
    float acc[4] = {0,0,0,0};
    float db[4]  = {0,0,0,0};
    #pragma unroll 8
    for (int d = 0; d < Dd; d++) {
      float mt = Mt[(size_t)d * Ee + e] + Mt[131072 + (size_t)d * Ee + e];
      float ud = uvec[d];
      #pragma unroll
      for (int si = 0; si < 4; si++) {
        float kv = xL[half*4 + si][d];
        acc[si] += mt * kv;
        db[si]  += ud * kv;
      }
    }
    const float scale = 0.044194173824159216f;  // 1/sqrt(512)
    const float te = tvec[e];
    const float bqbkv = bqbk[0];
    const int ks = e >> 5, gg = (e >> 3) & 3, j = e & 7;
    #pragma unroll
    for (int si = 0; si < 4; si++) {
      int sg = sbase + half*4 + si, bb_ = sg / 48, cc = sg % 48;
      int ct = cc >> 4, lane16 = (cc & 15) + 16*gg;
      unsigned short val = (cc < 40) ? f2bf(scale * (acc[si] + te)) : (unsigned short)0;
      abf[((((size_t)bb_*3 + ct)*16 + ks)*64 + lane16)*8 + j] = val;
      if (el == 0) dbias[bb_*64 + cc] = (cc < 40) ? scale * (db[si] + bqbkv) : 0.f;
    }
  } else {
    const int sbase = (blockIdx.x - 48) * 8;
    for (int i = t; i < 8 * Dd; i += 256) {
      int row = i >> 8, dd = i & (Dd - 1);
      int sg = sbase + row, bb_ = sg >> 6, cc = sg & 63;
      xL[row][dd] = (cc < 40) ? v[((size_t)bb_ * Cc + cc) * Dd + dd] : 0.f;
    }
    __syncthreads();
    const float* wrow = Wv + (size_t)e * Dd;
    float acc[4] = {0,0,0,0};
    #pragma unroll 2
    for (int dd = 0; dd < Dd; dd += 4) {
      float4 w = *(const float4*)(wrow + dd);
      #pragma unroll
      for (int si = 0; si < 4; si++) {
        float4 vv = *(const float4*)&xL[half*4 + si][dd];
        acc[si] += w.x*vv.x + w.y*vv.y + w.z*vv.z + w.w*vv.w;
      }
    }
    const float bve = bv[e];
    const int nt = e >> 4, elan = e & 15;
    #pragma unroll
    for (int si = 0; si < 4; si++) {
      int sg = sbase + half*4 + si, bb_ = sg >> 6, cc = sg & 63;
      int s = cc >> 5, gg = (cc >> 3) & 3, j = cc & 7;
      unsigned short val = (cc < 40) ? f2bf(acc[si] + bve) : (unsigned short)0;
      vpf[((((size_t)bb_*32 + nt)*2 + s)*64 + (elan + 16*gg))*8 + j] = val;
    }
  }
}

// ---------------- main: abf in LDS; vpf from L2; 8 waves/block; 2 blocks/CU ------
// grid 512: block = (b = bx>>6, seg = bx&63); block does 256 rows = 8w x 2it x 16.
// waves_per_eu(4,4): pin occupancy at 16 waves/CU so the allocator uses 128 VGPRs.
__global__ __launch_bounds__(512)
__attribute__((amdgpu_waves_per_eu(4, 4)))
void main_kernel(
    const float* __restrict__ q, const float* __restrict__ coarse,
    const unsigned short* __restrict__ abfrag,
    const unsigned short* __restrict__ vpfrag,
    const float* __restrict__ dbias, float* __restrict__ out) {
  __shared__ uint4 abL[3072];                   // 48 KB A-fragments (G)
  __shared__ unsigned short s_att[8][16][72];   // 18 KB per-wave attn re-fragment
  const int t = threadIdx.x;
  const int wave = t >> 6, lane = t & 63;
  const int r = lane & 15, g = lane >> 4;
  const int b = blockIdx.x >> 6;
  const int seg = blockIdx.x & 63;
  const bool v2 = (g < 2);

  const int row0 = seg * 256 + wave * 16;
  const float* qrow0 = q + ((size_t)b * Nn + row0 + r) * Ee + 8 * g;
  const float* cbase0 = coarse + (size_t)b * Cc * Nn + row0 + r;
  float* outb0 = out + ((size_t)b * Nn + row0 + r) * Ee + 4 * g;
  const bf16x8* vpb = (const bf16x8*)vpfrag + (size_t)b * 4096 + lane;

  float4 QA[4], QB[4];
  auto LOADQ = [&](const float* qr, int qi, float4* Q) {
    #pragma unroll
    for (int j = 0; j < 2; j++) {
      Q[2*j]   = *(const float4*)(qr + 128*qi + 64*j);
      Q[2*j+1] = *(const float4*)(qr + 128*qi + 64*j + 4);
    }
  };

  // ---- issue first q chunk BEFORE LDS staging (overlap) ----
  LOADQ(qrow0, 0, QA);

  // dbias (per batch, hoisted)
  const float4 db0 = *(const float4*)(dbias + b*64 +  0 + 4*g);
  const float4 db1 = *(const float4*)(dbias + b*64 + 16 + 4*g);
  const float4 db2 = *(const float4*)(dbias + b*64 + 32 + 4*g);

  // ---- stage A-fragments to LDS (once per block) ----
  {
    const uint4* srcA = (const uint4*)abfrag + (size_t)b * 3072;
    #pragma unroll
    for (int i = 0; i < 6; i++) abL[t + i*512] = srcA[t + i*512];
  }
  __syncthreads();

  f32x4 acc0, acc1, acc2;
  auto COMPQ = [&](const float4* Q, int qi) {
    #pragma unroll
    for (int j = 0; j < 2; j++) {
      bf16x8 qf = q2bf(Q[2*j], Q[2*j+1]);
      const int ks = 2*qi + j;
      acc0 = __builtin_amdgcn_mfma_f32_16x16x32_bf16(*(const bf16x8*)&abL[(0*16+ks)*64 + lane], qf, acc0, 0,0,0);
      acc1 = __builtin_amdgcn_mfma_f32_16x16x32_bf16(*(const bf16x8*)&abL[(1*16+ks)*64 + lane], qf, acc1, 0,0,0);
      acc2 = __builtin_amdgcn_mfma_f32_16x16x32_bf16(*(const bf16x8*)&abL[(2*16+ks)*64 + lane], qf, acc2, 0,0,0);
    }
  };

  for (int it = 0; it < 2; it++) {
    const float* qr = qrow0 + (size_t)(it*128) * Ee;
    LOADQ(qr, 1, QB);

    // coarse_pred loads (independent; latency hides under COMP)
    const float* cb = cbase0 + it*128;
    float cr[3][4];
    #pragma unroll
    for (int rg = 0; rg < 4; rg++) {
      cr[0][rg] = cb[(size_t)( 0 + 4*g + rg) * Nn];
      cr[1][rg] = cb[(size_t)(16 + 4*g + rg) * Nn];
      cr[2][rg] = v2 ? cb[(size_t)(32 + 4*g + rg) * Nn] : -3e38f;
    }

    acc0 = f32x4{0,0,0,0}; acc1 = f32x4{0,0,0,0}; acc2 = f32x4{0,0,0,0};
    COMPQ(QA, 0); LOADQ(qr, 2, QA);
    COMPQ(QB, 1); LOADQ(qr, 3, QB);
    COMPQ(QA, 2);
    // next-tile chunk 0 -> QA while QB still pending compute
    if (it < 1) LOADQ(qrow0 + (size_t)128 * Ee, 0, QA);
    COMPQ(QB, 3);
    // next-tile chunk 1 -> QB; 8 loads/lane now in flight through softmax+PV
    if (it < 1) LOADQ(qrow0 + (size_t)128 * Ee, 1, QB);

    float L[3][4];
    #pragma unroll
    for (int rg = 0; rg < 4; rg++) {
      L[0][rg] = acc0[rg] + ((const float*)&db0)[rg];
      L[1][rg] = acc1[rg] + ((const float*)&db1)[rg];
      L[2][rg] = acc2[rg] + ((const float*)&db2)[rg];
    }

    // ---- softmax #1 over c ----
    float m1 = -3e38f;
    #pragma unroll
    for (int rg = 0; rg < 4; rg++) {
      m1 = fmaxf(m1, L[0][rg]); m1 = fmaxf(m1, L[1][rg]);
      if (v2) m1 = fmaxf(m1, L[2][rg]);
    }
    m1 = fmaxf(m1, __shfl_xor(m1, 16));
    m1 = fmaxf(m1, __shfl_xor(m1, 32));
    float p[3][4]; float s1 = 0.f;
    #pragma unroll
    for (int rg = 0; rg < 4; rg++) {
      p[0][rg] = __expf(L[0][rg] - m1); s1 += p[0][rg];
      p[1][rg] = __expf(L[1][rg] - m1); s1 += p[1][rg];
      p[2][rg] = v2 ? __expf(L[2][rg] - m1) : 0.f; s1 += p[2][rg];
    }
    s1 += __shfl_xor(s1, 16); s1 += __shfl_xor(s1, 32);
    const float inv1 = 1.0f / s1;

    // ---- cp = softmax_c(coarse_pred) ----
    float m2 = -3e38f;
    #pragma unroll
    for (int rg = 0; rg < 4; rg++) {
      m2 = fmaxf(m2, cr[0][rg]); m2 = fmaxf(m2, cr[1][rg]);
      if (v2) m2 = fmaxf(m2, cr[2][rg]);
    }
    m2 = fmaxf(m2, __shfl_xor(m2, 16));
    m2 = fmaxf(m2, __shfl_xor(m2, 32));
    float cpv[3][4]; float s2 = 0.f;
    #pragma unroll
    for (int rg = 0; rg < 4; rg++) {
      cpv[0][rg] = __expf(cr[0][rg] - m2); s2 += cpv[0][rg];
      cpv[1][rg] = __expf(cr[1][rg] - m2); s2 += cpv[1][rg];
      cpv[2][rg] = v2 ? __expf(cr[2][rg] - m2) : 0.f; s2 += cpv[2][rg];
    }
    s2 += __shfl_xor(s2, 16); s2 += __shfl_xor(s2, 32);
    const float inv2 = 1.0f / s2;

    // ---- softmax #2 over c of (attn1 * cp) ----
    const float sc12 = inv1 * inv2;
    float w[3][4];
    float m3 = -3e38f;
    #pragma unroll
    for (int rg = 0; rg < 4; rg++) {
      w[0][rg] = p[0][rg] * cpv[0][rg] * sc12;
      w[1][rg] = p[1][rg] * cpv[1][rg] * sc12;
      w[2][rg] = v2 ? (p[2][rg] * cpv[2][rg] * sc12) : 0.f;
      m3 = fmaxf(m3, w[0][rg]); m3 = fmaxf(m3, w[1][rg]);
      if (v2) m3 = fmaxf(m3, w[2][rg]);
    }
    m3 = fmaxf(m3, __shfl_xor(m3, 16));
    m3 = fmaxf(m3, __shfl_xor(m3, 32));
    float p3[3][4]; float s3 = 0.f;
    #pragma unroll
    for (int rg = 0; rg < 4; rg++) {
      p3[0][rg] = __expf(w[0][rg] - m3); s3 += p3[0][rg];
      p3[1][rg] = __expf(w[1][rg] - m3); s3 += p3[1][rg];
      p3[2][rg] = v2 ? __expf(w[2][rg] - m3) : 0.f; s3 += p3[2][rg];
    }
    s3 += __shfl_xor(s3, 16); s3 += __shfl_xor(s3, 32);
    const float inv3 = 1.0f / s3;

    // ---- re-fragment attn2 via per-wave LDS round-trip ----
    unsigned int* srow = (unsigned int*)&s_att[wave][r][0];
    #pragma unroll
    for (int ct = 0; ct < 3; ct++) {
      srow[8*ct + 2*g + 0] = pack2(p3[ct][0]*inv3, p3[ct][1]*inv3);
      srow[8*ct + 2*g + 1] = pack2(p3[ct][2]*inv3, p3[ct][3]*inv3);
    }
    srow[24 + 2*g + 0] = 0u;   // c = 48..63 zero pad
    srow[24 + 2*g + 1] = 0u;
    asm volatile("s_waitcnt lgkmcnt(0)" ::: "memory");
    const bf16x8 pa0 = *(const bf16x8*)&s_att[wave][r][ 0 + 8*g];
    const bf16x8 pa1 = *(const bf16x8*)&s_att[wave][r][32 + 8*g];

    // ---- PV transposed, vpf from L2, depth-2 register pipeline ----
    float* outp = outb0 + (size_t)(it*128) * Ee;
    bf16x8 va0 = vpb[0], va1 = vpb[64];
    #pragma unroll
    for (int nt = 0; nt < 32; nt++) {
      bf16x8 vb0, vb1;
      if (nt < 31) { vb0 = vpb[(nt+1)*128]; vb1 = vpb[(nt+1)*128 + 64]; }
      f32x4 o = {0,0,0,0};
      o = __builtin_amdgcn_mfma_f32_16x16x32_bf16(va0, pa0, o, 0,0,0);
      o = __builtin_amdgcn_mfma_f32_16x16x32_bf16(va1, pa1, o, 0,0,0);
      *(f32x4*)(outp + nt*16) = o;   // out[row r][nt*16 + 4g .. +3]
      va0 = vb0; va1 = vb1;
    }
  }
}

extern "C" void kernel_launch(void* const* d_in, const int* in_sizes, int n_in,
                              void* d_out, int out_size, void* d_ws, size_t ws_size,
                              hipStream_t stream) {
  const float* q   = (const float*)d_in[0];
  const float* k   = (const float*)d_in[1];
  const float* v   = (const float*)d_in[2];
  const float* cps = (const float*)d_in[3];
  const float* Wq  = (const float*)d_in[4];
  const float* bq  = (const float*)d_in[5];
  const float* Wk  = (const float*)d_in[6];
  const float* bk  = (const float*)d_in[7];
  const float* Wv  = (const float*)d_in[8];
  const float* bv  = (const float*)d_in[9];
  float* out = (float*)d_out;
  char* ws = (char*)d_ws;

  // ws layout (~1.97 MB total)
  float*          Mt    = (float*)(ws);                        // 2*256*512*4 = 1048576
  float*          tvec  = (float*)(ws + 1048576);              // 512*4  = 2048
  float*          uvec  = (float*)(ws + 1050624);              // 256*4  = 1024
  float*          bqbkp = (float*)(ws + 1051648);              // 4 (pad to 1024)
  unsigned short* abf   = (unsigned short*)(ws + 1052672);     // 393216
  unsigned short* vpf   = (unsigned short*)(ws + 1052672 + 393216);          // 524288
  float*          dbias = (float*)(ws + 1052672 + 393216 + 524288);          // 2048

  prepA_kernel<<<dim3(9, 4, 2), 256, 0, stream>>>(Wq, Wk, bq, bk, Mt, tvec, uvec, bqbkp);
  prepB_kernel<<<dim3(112, 4),  256, 0, stream>>>(k, v, Wv, bv, Mt, tvec, uvec, bqbkp,
                                                  abf, vpf, dbias);
  main_kernel <<<dim3(512),     512, 0, stream>>>(q, cps, abf, vpf, dbias, out);
}

// Round 8
// 173.803 us; speedup vs baseline: 1.6660x; 1.2262x over previous
//
#include <hip/hip_runtime.h>
#include <hip/hip_bf16.h>
#include <stdint.h>

#define Bb 8
#define Nn 16384
#define Cc 40
#define Ee 512
#define Dd 256

typedef __attribute__((ext_vector_type(4))) float f32x4;
typedef __attribute__((ext_vector_type(8))) short bf16x8;

__device__ __forceinline__ unsigned short f2bf(float f) {
  union { float f; uint32_t u; } x; x.f = f;
  uint32_t r = x.u + 0x7FFFu + ((x.u >> 16) & 1u);   // round-to-nearest-even
  return (unsigned short)(r >> 16);
}
__device__ __forceinline__ unsigned int pack2(float a, float b) {
  return (unsigned int)f2bf(a) | ((unsigned int)f2bf(b) << 16);
}
__device__ __forceinline__ bf16x8 q2bf(float4 a, float4 c) {
  union { __hip_bfloat162 h2[4]; bf16x8 v; } u;
  u.h2[0] = __float22bfloat162_rn(float2{a.x, a.y});
  u.h2[1] = __float22bfloat162_rn(float2{a.z, a.w});
  u.h2[2] = __float22bfloat162_rn(float2{c.x, c.y});
  u.h2[3] = __float22bfloat162_rn(float2{c.z, c.w});
  return u.v;
}

// ---------------- prepA: Mt[z][d][e] = sum_{f half z} Wq[f][e]*Wk[f][d];
//                  plus (bx==8,bz==0): tvec/uvec/bqbk bias vectors ----------------
// grid (9,4,2), 256 thr.
__global__ __launch_bounds__(256) void prepA_kernel(
    const float* __restrict__ Wq, const float* __restrict__ Wk,
    const float* __restrict__ bq, const float* __restrict__ bk,
    float* __restrict__ Mt, float* __restrict__ tvec,
    float* __restrict__ uvec, float* __restrict__ bqbk) {
  const int t = threadIdx.x;
  if (blockIdx.x == 8) {
    if (blockIdx.z != 0) return;
    const int by = blockIdx.y;
    if (by < 2) {
      const int e = by * 256 + t;
      float s = 0.f;
      #pragma unroll 8
      for (int f = 0; f < Ee; f++) s += Wq[(size_t)f * Ee + e] * bk[f];
      tvec[e] = s;
    } else if (by == 2) {
      const int d = t;
      float s = 0.f;
      #pragma unroll 8
      for (int f = 0; f < Ee; f++) s += Wk[(size_t)f * Dd + d] * bq[f];
      uvec[d] = s;
    } else {
      __shared__ float red[256];
      float p = 0.f;
      for (int f = t; f < Ee; f += 256) p += bq[f] * bk[f];
      red[t] = p; __syncthreads();
      #pragma unroll
      for (int off = 128; off > 0; off >>= 1) {
        if (t < off) red[t] += red[t + off];
        __syncthreads();
      }
      if (t == 0) bqbk[0] = red[0];
    }
    return;
  }
  __shared__ float WqL[64][68];
  __shared__ float WkL[64][68];
  const int te = (t & 15) * 4;
  const int td = (t >> 4) * 4;
  const int ebase = blockIdx.x * 64, dbase = blockIdx.y * 64;
  const int fbase = blockIdx.z * 256;
  f32x4 acc0 = {0,0,0,0}, acc1 = {0,0,0,0}, acc2 = {0,0,0,0}, acc3 = {0,0,0,0};
  for (int f0 = 0; f0 < 256; f0 += 64) {
    __syncthreads();
    #pragma unroll
    for (int i = 0; i < 4; i++) {
      int idx = t + i * 256;
      int row = idx >> 4, c4 = (idx & 15) * 4;
      *(float4*)&WqL[row][c4] = *(const float4*)(Wq + (size_t)(fbase + f0 + row) * Ee + ebase + c4);
      *(float4*)&WkL[row][c4] = *(const float4*)(Wk + (size_t)(fbase + f0 + row) * Dd + dbase + c4);
    }
    __syncthreads();
    #pragma unroll 8
    for (int ff = 0; ff < 64; ff++) {
      float4 a = *(const float4*)&WkL[ff][td];
      float4 b = *(const float4*)&WqL[ff][te];
      acc0[0] += a.x*b.x; acc0[1] += a.x*b.y; acc0[2] += a.x*b.z; acc0[3] += a.x*b.w;
      acc1[0] += a.y*b.x; acc1[1] += a.y*b.y; acc1[2] += a.y*b.z; acc1[3] += a.y*b.w;
      acc2[0] += a.z*b.x; acc2[1] += a.z*b.y; acc2[2] += a.z*b.z; acc2[3] += a.z*b.w;
      acc3[0] += a.w*b.x; acc3[1] += a.w*b.y; acc3[2] += a.w*b.z; acc3[3] += a.w*b.w;
    }
  }
  float* mt = Mt + (size_t)blockIdx.z * 131072;
  *(f32x4*)&mt[(size_t)(dbase + td + 0) * Ee + ebase + te] = acc0;
  *(f32x4*)&mt[(size_t)(dbase + td + 1) * Ee + ebase + te] = acc1;
  *(f32x4*)&mt[(size_t)(dbase + td + 2) * Ee + ebase + te] = acc2;
  *(f32x4*)&mt[(size_t)(dbase + td + 3) * Ee + ebase + te] = acc3;
}

// ---------------- prepB: bx<48 -> A-frags(G)+dbias; bx>=48 -> B-frags(vp) --------
// grid (112,4), 256 thr.
__global__ __launch_bounds__(256) void prepB_kernel(
    const float* __restrict__ k, const float* __restrict__ v,
    const float* __restrict__ Wv, const float* __restrict__ bv,
    const float* __restrict__ Mt, const float* __restrict__ tvec,
    const float* __restrict__ uvec, const float* __restrict__ bqbk,
    unsigned short* __restrict__ abf, unsigned short* __restrict__ vpf,
    float* __restrict__ dbias) {
  __shared__ float xL[8][Dd];
  const int t = threadIdx.x;
  const int el = t & 127, half = t >> 7;
  const int e = blockIdx.y * 128 + el;

  if (blockIdx.x < 48) {
    const int sbase = blockIdx.x * 8;
    for (int i = t; i < 8 * Dd; i += 256) {
      int row = i >> 8, dd = i & (Dd - 1);
      int sg = sbase + row, bb_ = sg / 48, cc = sg % 48;
      xL[row][dd] = (cc < 40) ? k[((size_t)bb_ * Cc + cc) * Dd + dd] : 0.f;
    }
    __syncthreads();
    float acc[4] = {0,0,0,0};
    float db[4]  = {0,0,0,0};
    #pragma unroll 8
    for (int d = 0; d < Dd; d++) {
      float mt = Mt[(size_t)d * Ee + e] + Mt[131072 + (size_t)d * Ee + e];
      float ud = uvec[d];
      #pragma unroll
      for (int si = 0; si < 4; si++) {
        float kv = xL[half*4 + si][d];
        acc[si] += mt * kv;
        db[si]  += ud * kv;
      }
    }
    const float scale = 0.044194173824159216f;  // 1/sqrt(512)
    const float te = tvec[e];
    const float bqbkv = bqbk[0];
    const int ks = e >> 5, gg = (e >> 3) & 3, j = e & 7;
    #pragma unroll
    for (int si = 0; si < 4; si++) {
      int sg = sbase + half*4 + si, bb_ = sg / 48, cc = sg % 48;
      int ct = cc >> 4, lane16 = (cc & 15) + 16*gg;
      unsigned short val = (cc < 40) ? f2bf(scale * (acc[si] + te)) : (unsigned short)0;
      abf[((((size_t)bb_*3 + ct)*16 + ks)*64 + lane16)*8 + j] = val;
      if (el == 0) dbias[bb_*64 + cc] = (cc < 40) ? scale * (db[si] + bqbkv) : 0.f;
    }
  } else {
    const int sbase = (blockIdx.x - 48) * 8;
    for (int i = t; i < 8 * Dd; i += 256) {
      int row = i >> 8, dd = i & (Dd - 1);
      int sg = sbase + row, bb_ = sg >> 6, cc = sg & 63;
      xL[row][dd] = (cc < 40) ? v[((size_t)bb_ * Cc + cc) * Dd + dd] : 0.f;
    }
    __syncthreads();
    const float* wrow = Wv + (size_t)e * Dd;
    float acc[4] = {0,0,0,0};
    #pragma unroll 2
    for (int dd = 0; dd < Dd; dd += 4) {
      float4 w = *(const float4*)(wrow + dd);
      #pragma unroll
      for (int si = 0; si < 4; si++) {
        float4 vv = *(const float4*)&xL[half*4 + si][dd];
        acc[si] += w.x*vv.x + w.y*vv.y + w.z*vv.z + w.w*vv.w;
      }
    }
    const float bve = bv[e];
    const int nt = e >> 4, elan = e & 15;
    #pragma unroll
    for (int si = 0; si < 4; si++) {
      int sg = sbase + half*4 + si, bb_ = sg >> 6, cc = sg & 63;
      int s = cc >> 5, gg = (cc >> 3) & 3, j = cc & 7;
      unsigned short val = (cc < 40) ? f2bf(acc[si] + bve) : (unsigned short)0;
      vpf[((((size_t)bb_*32 + nt)*2 + s)*64 + (elan + 16*gg))*8 + j] = val;
    }
  }
}

// ---------------- main: abf+vpf in LDS (112KB); 8 waves/block; zero-spill q pipe -
// grid 256: block = (b = bx>>5, seg = bx&31); 4 iters x 8 waves x 16 rows = 512.
__global__ __launch_bounds__(512) void main_kernel(
    const float* __restrict__ q, const float* __restrict__ coarse,
    const unsigned short* __restrict__ abfrag,
    const unsigned short* __restrict__ vpfrag,
    const float* __restrict__ dbias, float* __restrict__ out) {
  __shared__ uint4 fragL[7168];                 // 112 KB: [0,3072)=abf, [3072,7168)=vpf
  __shared__ unsigned short s_att[8][16][72];   // 18 KB per-wave attn re-fragment
  const int t = threadIdx.x;
  const int wave = t >> 6, lane = t & 63;
  const int r = lane & 15, g = lane >> 4;
  const int b = blockIdx.x >> 5;
  const int seg = blockIdx.x & 31;
  const bool v2 = (g < 2);

  // ---- stage fragments to LDS (once per block) ----
  {
    const uint4* srcA = (const uint4*)abfrag + (size_t)b * 3072;
    #pragma unroll
    for (int i = 0; i < 6; i++) fragL[t + i*512] = srcA[t + i*512];
    const uint4* srcV = (const uint4*)vpfrag + (size_t)b * 4096;
    #pragma unroll
    for (int i = 0; i < 8; i++) fragL[3072 + t + i*512] = srcV[t + i*512];
  }
  __syncthreads();

  const int row0 = seg * 512 + wave * 16;
  const float* qrow0 = q + ((size_t)b * Nn + row0 + r) * Ee + 8 * g;
  const float* cbase0 = coarse + (size_t)b * Cc * Nn + row0 + r;
  float* outb0 = out + ((size_t)b * Nn + row0 + r) * Ee + 4 * g;

  for (int it = 0; it < 4; it++) {
    const float* qr = qrow0 + (size_t)(it*128) * Ee;
    f32x4 acc0 = {0,0,0,0}, acc1 = {0,0,0,0}, acc2 = {0,0,0,0};

    // rolling depth-2 q chunks: chunk c = K columns 64c..64c+63 (2 MFMA k-steps)
    float4 a0, a1, a2, a3, b0, b1, b2, b3;
    auto LD_A = [&](int c) {
      a0 = *(const float4*)(qr + 64*c);
      a1 = *(const float4*)(qr + 64*c + 4);
      a2 = *(const float4*)(qr + 64*c + 32);
      a3 = *(const float4*)(qr + 64*c + 36);
    };
    auto LD_B = [&](int c) {
      b0 = *(const float4*)(qr + 64*c);
      b1 = *(const float4*)(qr + 64*c + 4);
      b2 = *(const float4*)(qr + 64*c + 32);
      b3 = *(const float4*)(qr + 64*c + 36);
    };
    auto MM = [&](int c, float4 x0, float4 x1, float4 x2, float4 x3) {
      bf16x8 q0 = q2bf(x0, x1), q1 = q2bf(x2, x3);
      const int ks = 2*c;
      acc0 = __builtin_amdgcn_mfma_f32_16x16x32_bf16(*(const bf16x8*)&fragL[(0*16+ks)*64 + lane], q0, acc0, 0,0,0);
      acc1 = __builtin_amdgcn_mfma_f32_16x16x32_bf16(*(const bf16x8*)&fragL[(1*16+ks)*64 + lane], q0, acc1, 0,0,0);
      acc2 = __builtin_amdgcn_mfma_f32_16x16x32_bf16(*(const bf16x8*)&fragL[(2*16+ks)*64 + lane], q0, acc2, 0,0,0);
      acc0 = __builtin_amdgcn_mfma_f32_16x16x32_bf16(*(const bf16x8*)&fragL[(0*16+ks+1)*64 + lane], q1, acc0, 0,0,0);
      acc1 = __builtin_amdgcn_mfma_f32_16x16x32_bf16(*(const bf16x8*)&fragL[(1*16+ks+1)*64 + lane], q1, acc1, 0,0,0);
      acc2 = __builtin_amdgcn_mfma_f32_16x16x32_bf16(*(const bf16x8*)&fragL[(2*16+ks+1)*64 + lane], q1, acc2, 0,0,0);
    };

    LD_A(0);
    LD_B(1);

    // coarse_pred loads (independent; latency hides under QK MFMAs)
    const float* cb = cbase0 + it*128;
    float cr[3][4];
    #pragma unroll
    for (int rg = 0; rg < 4; rg++) {
      cr[0][rg] = cb[(size_t)( 0 + 4*g + rg) * Nn];
      cr[1][rg] = cb[(size_t)(16 + 4*g + rg) * Nn];
      cr[2][rg] = v2 ? cb[(size_t)(32 + 4*g + rg) * Nn] : -3e38f;
    }

    MM(0, a0,a1,a2,a3); LD_A(2);
    MM(1, b0,b1,b2,b3); LD_B(3);
    MM(2, a0,a1,a2,a3); LD_A(4);
    MM(3, b0,b1,b2,b3); LD_B(5);
    MM(4, a0,a1,a2,a3); LD_A(6);
    MM(5, b0,b1,b2,b3); LD_B(7);
    MM(6, a0,a1,a2,a3);
    MM(7, b0,b1,b2,b3);

    // dbias (L2-hot after iter 0; short live range)
    const float4 db0 = *(const float4*)(dbias + b*64 +  0 + 4*g);
    const float4 db1 = *(const float4*)(dbias + b*64 + 16 + 4*g);
    const float4 db2 = *(const float4*)(dbias + b*64 + 32 + 4*g);

    // x: L -> p -> w -> p3, all in place
    float x[3][4];
    #pragma unroll
    for (int rg = 0; rg < 4; rg++) {
      x[0][rg] = acc0[rg] + ((const float*)&db0)[rg];
      x[1][rg] = acc1[rg] + ((const float*)&db1)[rg];
      x[2][rg] = acc2[rg] + ((const float*)&db2)[rg];
    }

    // ---- softmax #1 over c ----
    float m1 = -3e38f;
    #pragma unroll
    for (int rg = 0; rg < 4; rg++) {
      m1 = fmaxf(m1, x[0][rg]); m1 = fmaxf(m1, x[1][rg]);
      if (v2) m1 = fmaxf(m1, x[2][rg]);
    }
    m1 = fmaxf(m1, __shfl_xor(m1, 16));
    m1 = fmaxf(m1, __shfl_xor(m1, 32));
    float s1 = 0.f;
    #pragma unroll
    for (int rg = 0; rg < 4; rg++) {
      x[0][rg] = __expf(x[0][rg] - m1); s1 += x[0][rg];
      x[1][rg] = __expf(x[1][rg] - m1); s1 += x[1][rg];
      x[2][rg] = v2 ? __expf(x[2][rg] - m1) : 0.f; s1 += x[2][rg];
    }
    s1 += __shfl_xor(s1, 16); s1 += __shfl_xor(s1, 32);

    // ---- cp = softmax_c(coarse_pred), in place into cr ----
    float m2 = -3e38f;
    #pragma unroll
    for (int rg = 0; rg < 4; rg++) {
      m2 = fmaxf(m2, cr[0][rg]); m2 = fmaxf(m2, cr[1][rg]);
      if (v2) m2 = fmaxf(m2, cr[2][rg]);
    }
    m2 = fmaxf(m2, __shfl_xor(m2, 16));
    m2 = fmaxf(m2, __shfl_xor(m2, 32));
    float s2 = 0.f;
    #pragma unroll
    for (int rg = 0; rg < 4; rg++) {
      cr[0][rg] = __expf(cr[0][rg] - m2); s2 += cr[0][rg];
      cr[1][rg] = __expf(cr[1][rg] - m2); s2 += cr[1][rg];
      cr[2][rg] = v2 ? __expf(cr[2][rg] - m2) : 0.f; s2 += cr[2][rg];
    }
    s2 += __shfl_xor(s2, 16); s2 += __shfl_xor(s2, 32);

    // ---- softmax #2 over c of (attn1 * cp), in place into x ----
    const float sc12 = 1.0f / (s1 * s2);
    float m3 = -3e38f;
    #pragma unroll
    for (int rg = 0; rg < 4; rg++) {
      x[0][rg] *= cr[0][rg] * sc12;
      x[1][rg] *= cr[1][rg] * sc12;
      x[2][rg] = v2 ? (x[2][rg] * cr[2][rg] * sc12) : 0.f;
      m3 = fmaxf(m3, x[0][rg]); m3 = fmaxf(m3, x[1][rg]);
      if (v2) m3 = fmaxf(m3, x[2][rg]);
    }
    m3 = fmaxf(m3, __shfl_xor(m3, 16));
    m3 = fmaxf(m3, __shfl_xor(m3, 32));
    float s3 = 0.f;
    #pragma unroll
    for (int rg = 0; rg < 4; rg++) {
      x[0][rg] = __expf(x[0][rg] - m3); s3 += x[0][rg];
      x[1][rg] = __expf(x[1][rg] - m3); s3 += x[1][rg];
      x[2][rg] = v2 ? __expf(x[2][rg] - m3) : 0.f; s3 += x[2][rg];
    }
    s3 += __shfl_xor(s3, 16); s3 += __shfl_xor(s3, 32);
    const float inv3 = 1.0f / s3;

    // ---- re-fragment attn2 via per-wave LDS round-trip ----
    unsigned int* srow = (unsigned int*)&s_att[wave][r][0];
    #pragma unroll
    for (int ct = 0; ct < 3; ct++) {
      srow[8*ct + 2*g + 0] = pack2(x[ct][0]*inv3, x[ct][1]*inv3);
      srow[8*ct + 2*g + 1] = pack2(x[ct][2]*inv3, x[ct][3]*inv3);
    }
    srow[24 + 2*g + 0] = 0u;   // c = 48..63 zero pad
    srow[24 + 2*g + 1] = 0u;
    asm volatile("s_waitcnt lgkmcnt(0)" ::: "memory");
    const bf16x8 pa0 = *(const bf16x8*)&s_att[wave][r][ 0 + 8*g];
    const bf16x8 pa1 = *(const bf16x8*)&s_att[wave][r][32 + 8*g];

    // ---- PV transposed from LDS: outT = vp^T @ attn^T; float4 stores ----
    float* outp = outb0 + (size_t)(it*128) * Ee;
    #pragma unroll 8
    for (int nt = 0; nt < 32; nt++) {
      bf16x8 vf0 = *(const bf16x8*)&fragL[3072 + (nt*2 + 0)*64 + lane];
      bf16x8 vf1 = *(const bf16x8*)&fragL[3072 + (nt*2 + 1)*64 + lane];
      f32x4 o = {0,0,0,0};
      o = __builtin_amdgcn_mfma_f32_16x16x32_bf16(vf0, pa0, o, 0,0,0);
      o = __builtin_amdgcn_mfma_f32_16x16x32_bf16(vf1, pa1, o, 0,0,0);
      *(f32x4*)(outp + nt*16) = o;   // out[row r][nt*16 + 4g .. +3]
    }
  }
}

extern "C" void kernel_launch(void* const* d_in, const int* in_sizes, int n_in,
                              void* d_out, int out_size, void* d_ws, size_t ws_size,
                              hipStream_t stream) {
  const float* q   = (const float*)d_in[0];
  const float* k   = (const float*)d_in[1];
  const float* v   = (const float*)d_in[2];
  const float* cps = (const float*)d_in[3];
  const float* Wq  = (const float*)d_in[4];
  const float* bq  = (const float*)d_in[5];
  const float* Wk  = (const float*)d_in[6];
  const float* bk  = (const float*)d_in[7];
  const float* Wv  = (const float*)d_in[8];
  const float* bv  = (const float*)d_in[9];
  float* out = (float*)d_out;
  char* ws = (char*)d_ws;

  // ws layout (~1.97 MB total)
  float*          Mt    = (float*)(ws);                        // 2*256*512*4 = 1048576
  float*          tvec  = (float*)(ws + 1048576);              // 512*4  = 2048
  float*          uvec  = (float*)(ws + 1050624);              // 256*4  = 1024
  float*          bqbkp = (float*)(ws + 1051648);              // 4 (pad to 1024)
  unsigned short* abf   = (unsigned short*)(ws + 1052672);     // 393216
  unsigned short* vpf   = (unsigned short*)(ws + 1052672 + 393216);          // 524288
  float*          dbias = (float*)(ws + 1052672 + 393216 + 524288);          // 2048

  prepA_kernel<<<dim3(9, 4, 2), 256, 0, stream>>>(Wq, Wk, bq, bk, Mt, tvec, uvec, bqbkp);
  prepB_kernel<<<dim3(112, 4),  256, 0, stream>>>(k, v, Wv, bv, Mt, tvec, uvec, bqbkp,
                                                  abf, vpf, dbias);
  main_kernel <<<dim3(256),     512, 0, stream>>>(q, cps, abf, vpf, dbias, out);
}